// Round 5
// baseline (111914.795 us; speedup 1.0000x reference)
//
#include <hip/hip_runtime.h>
#include <math.h>

#define NB 32
#define NS 512
#define NE 1024
#define NAA 2
#define NH 1024
#define NZ 512
#define NL 64
#define NH3 3072
#define NCQ 2112
#define NCP 1088

// output layout (floats): h_seq, sp, mp, gp, h_seq(dup), sq, mq, gq
static constexpr size_t SZH = (size_t)NB * NS * NH;
static constexpr size_t SZZ = (size_t)NB * NS * NZ;
static constexpr size_t OH1 = 0;
static constexpr size_t OSP = SZH;
static constexpr size_t OMP = OSP + SZZ;
static constexpr size_t OGP = OMP + SZZ;
static constexpr size_t OH2 = OGP + SZZ;
static constexpr size_t OSQ = OH2 + SZH;
static constexpr size_t OMQ = OSQ + SZZ;
static constexpr size_t OGQ = OMQ + SZZ;

#define LSTR 260   // LDS x-buffer row stride (floats); stride%32=4 -> 8 bgrp addrs hit disjoint bank groups
#define PSTR 25    // partials row stride (floats)
#define XBUFSZ (NB * LSTR)   // 8320 floats per buffer

static __device__ __forceinline__ float lrelu(float v) { return v >= 0.f ? v : 0.01f * v; }
static __device__ __forceinline__ float sigm(float v)  { return 1.f / (1.f + expf(-v)); }

struct Seg {
  const float* src;   // batch-row base
  size_t bstride;     // element stride between batch rows
  int wcol;           // starting weight-column of this segment
  int len;            // segment length (floats); multiple of 256, or 64 tail
};

// ---------------------------------------------------------------------------
// Grid barrier: fresh counter per barrier (zeroed ws), bounded spin + poison.
// ---------------------------------------------------------------------------
static __device__ __forceinline__ void gbar(unsigned* cnt, unsigned* brk) {
  __syncthreads();
  if (threadIdx.x == 0) {
    __threadfence();                       // release my block's writes
    atomicAdd(cnt, 1u);
    unsigned it = 0;
    while (__hip_atomic_load(cnt, __ATOMIC_ACQUIRE, __HIP_MEMORY_SCOPE_AGENT) < 256u) {
      if (__hip_atomic_load(brk, __ATOMIC_RELAXED, __HIP_MEMORY_SCOPE_AGENT) != 0u) break;
      if (++it > 60000000u) {              // ~1.6 s: turn deadlock into finite failure
        __hip_atomic_store(brk, 1u, __ATOMIC_RELAXED, __HIP_MEMORY_SCOPE_AGENT);
        break;
      }
      __builtin_amdgcn_s_sleep(1);
    }
  }
  __syncthreads();
}

// ---------------------------------------------------------------------------
// Tile GEMM: out-tile = 32 b x (8*NC) cols, K walked in pow2 chunks (<=256)
// over up to 3 concat segments. x staged in LDS (double-buffered, load-early/
// write-late, 1 intra-block barrier per chunk). Weights streamed from global.
// Lane map: col = lane&7 (thread cols: col + c*8, c<NC), bgrp = lane>>3,
// thread b's: bgrp + j*8 (j<4). Wave wid takes k-slice [wid*clen/8, ...).
// Partials written to part[wid][b*PSTR + col + c*8]; caller reduces over wid.
// ---------------------------------------------------------------------------
template<int NC>
static __device__ __forceinline__ void tile_gemm(
    const Seg* __restrict__ sg, int nch,
    const float* __restrict__ W, int KW, const int* __restrict__ rows,
    float* __restrict__ xb /*2 bufs*/, float* __restrict__ part)
{
  const int tid  = threadIdx.x;
  const int lane = tid & 63, wid = tid >> 6;
  const int col  = lane & 7;
  const int bgrp = lane >> 3;

  float acc[4][NC];
  #pragma unroll
  for (int j = 0; j < 4; ++j)
    #pragma unroll
    for (int c = 0; c < NC; ++c) acc[j][c] = 0.f;

  const float* wrow[NC];
  #pragma unroll
  for (int c = 0; c < NC; ++c) wrow[c] = W + (size_t)rows[c] * KW;

  // chunk state
  int si = 0, off = 0;
  int clen = sg[0].len; if (clen > 256) clen = 256;

  float4 r0, r1, r2, r3;
  { // prologue: issue loads for chunk 0
    const Seg& S = sg[0];
    const int sh = (clen == 256) ? 8 : 6;
    int idx = tid * 4; int bb = idx >> sh; int kk = idx & (clen - 1);
    r0 = *(const float4*)(S.src + (size_t)bb * S.bstride + off + kk);
    if (clen == 256) {
      idx = 2048 + tid * 4; bb = idx >> 8; kk = idx & 255;
      r1 = *(const float4*)(S.src + (size_t)bb * S.bstride + off + kk);
      idx = 4096 + tid * 4; bb = idx >> 8; kk = idx & 255;
      r2 = *(const float4*)(S.src + (size_t)bb * S.bstride + off + kk);
      idx = 6144 + tid * 4; bb = idx >> 8; kk = idx & 255;
      r3 = *(const float4*)(S.src + (size_t)bb * S.bstride + off + kk);
    }
  }

  for (int ci = 0; ci < nch; ++ci) {
    const int cur_clen = clen, cur_si = si, cur_off = off;
    float* buf = xb + (ci & 1) * XBUFSZ;
    { // write staged regs into buf
      const int sh = (cur_clen == 256) ? 8 : 6;
      int idx = tid * 4; int bb = idx >> sh; int kk = idx & (cur_clen - 1);
      *(float4*)(buf + bb * LSTR + kk) = r0;
      if (cur_clen == 256) {
        idx = 2048 + tid * 4; bb = idx >> 8; kk = idx & 255; *(float4*)(buf + bb * LSTR + kk) = r1;
        idx = 4096 + tid * 4; bb = idx >> 8; kk = idx & 255; *(float4*)(buf + bb * LSTR + kk) = r2;
        idx = 6144 + tid * 4; bb = idx >> 8; kk = idx & 255; *(float4*)(buf + bb * LSTR + kk) = r3;
      }
    }
    __syncthreads();   // buf[ci&1] fully staged for all waves

    // advance state + issue loads for next chunk (lands during compute below)
    int nsi = si, noff = off + cur_clen;
    if (noff >= sg[si].len) { nsi = si + 1; noff = 0; }
    if (ci + 1 < nch) {
      int nclen = sg[nsi].len - noff; if (nclen > 256) nclen = 256;
      const Seg& S = sg[nsi];
      const int sh = (nclen == 256) ? 8 : 6;
      int idx = tid * 4; int bb = idx >> sh; int kk = idx & (nclen - 1);
      r0 = *(const float4*)(S.src + (size_t)bb * S.bstride + noff + kk);
      if (nclen == 256) {
        idx = 2048 + tid * 4; bb = idx >> 8; kk = idx & 255;
        r1 = *(const float4*)(S.src + (size_t)bb * S.bstride + noff + kk);
        idx = 4096 + tid * 4; bb = idx >> 8; kk = idx & 255;
        r2 = *(const float4*)(S.src + (size_t)bb * S.bstride + noff + kk);
        idx = 6144 + tid * 4; bb = idx >> 8; kk = idx & 255;
        r3 = *(const float4*)(S.src + (size_t)bb * S.bstride + noff + kk);
      }
      clen = nclen;
    }
    si = nsi; off = noff;

    // compute current chunk
    const int wk = sg[cur_si].wcol + cur_off;
    const int slice = cur_clen >> 3;
    const int ks = wid * slice;
    #pragma unroll 2
    for (int i = 0; i < slice; i += 4) {
      const int kk = ks + i;
      float4 wv[NC];
      #pragma unroll
      for (int c = 0; c < NC; ++c) wv[c] = *(const float4*)(wrow[c] + wk + kk);
      #pragma unroll
      for (int j = 0; j < 4; ++j) {
        const float4 xv = *(const float4*)(buf + (bgrp + j * 8) * LSTR + kk);
        #pragma unroll
        for (int c = 0; c < NC; ++c) {
          acc[j][c] = fmaf(wv[c].x, xv.x, acc[j][c]);
          acc[j][c] = fmaf(wv[c].y, xv.y, acc[j][c]);
          acc[j][c] = fmaf(wv[c].z, xv.z, acc[j][c]);
          acc[j][c] = fmaf(wv[c].w, xv.w, acc[j][c]);
        }
      }
    }
    // no trailing barrier: next iteration writes the OTHER buffer, and its
    // pre-write barrier orders against all waves' compute of this chunk.
  }

  // partials -> LDS
  #pragma unroll
  for (int j = 0; j < 4; ++j) {
    const int b = bgrp + j * 8;
    #pragma unroll
    for (int c = 0; c < NC; ++c)
      part[wid * (NB * PSTR) + b * PSTR + col + c * 8] = acc[j][c];
  }
  __syncthreads();
}

static __device__ __forceinline__ float reduce8(const float* __restrict__ part, int b, int c) {
  float v = 0.f;
  #pragma unroll
  for (int w = 0; w < 8; ++w) v += part[w * (NB * PSTR) + b * PSTR + c];
  return v;
}

// ---------------------------------------------------------------------------
__global__ __launch_bounds__(512, 1) void rssm_persist(
    const float* __restrict__ emb, const float* __restrict__ act,
    const float* __restrict__ npr, const float* __restrict__ npo,
    const float* __restrict__ preW, const float* __restrict__ preb,
    const float* __restrict__ Wih, const float* __restrict__ Whh,
    const float* __restrict__ bih, const float* __restrict__ bhh,
    const float* __restrict__ qactW, const float* __restrict__ qactb,
    const float* __restrict__ pactW, const float* __restrict__ pactb,
    const float* __restrict__ W1q, const float* __restrict__ b1q,
    const float* __restrict__ W2q, const float* __restrict__ b2q,
    const float* __restrict__ W1p, const float* __restrict__ b1p,
    const float* __restrict__ W2p, const float* __restrict__ b2p,
    float* __restrict__ out,
    float* __restrict__ s_ws, float* __restrict__ h_ws,
    float* __restrict__ x_ws, float* __restrict__ gh_ws,
    float* __restrict__ lap_ws, float* __restrict__ laq_ws,
    float* __restrict__ hmq_ws, float* __restrict__ hmp_ws,
    unsigned* __restrict__ cntb, unsigned* __restrict__ brk)
{
  __shared__ float xbuf[2 * XBUFSZ];        // 66560 B
  __shared__ float part[8 * NB * PSTR];     // 25600 B
  const int tid = threadIdx.x;
  const int bid = blockIdx.x;
  const int colsel = tid & 7;

  for (int t = 0; t < NS; ++t) {
    // ---------------- Phase A: x = lrelu(s@preW^T+b); gh = h@Whh^T+b -------
    if (bid < 64) {
      const int colg = bid * 16;
      Seg sg[1]; sg[0] = { s_ws, (size_t)NZ, 0, NZ };
      int rows[2] = { colg + colsel, colg + colsel + 8 };
      tile_gemm<2>(sg, 2, preW, NZ, rows, xbuf, part);
      const int b = tid >> 4, c = tid & 15;
      const float v = reduce8(part, b, c) + preb[colg + c];
      x_ws[b * NH + colg + c] = lrelu(v);
    } else {
      const int colg = (bid - 64) * 16;
      Seg sg[1]; sg[0] = { h_ws, (size_t)NH, 0, NH };
      int rows[2] = { colg + colsel, colg + colsel + 8 };
      tile_gemm<2>(sg, 4, Whh, NH, rows, xbuf, part);
      const int b = tid >> 4, c = tid & 15;
      gh_ws[b * NH3 + colg + c] = reduce8(part, b, c) + bhh[colg + c];
    }
    gbar(cntb + (size_t)(t * 4 + 0) * 16, brk);

    // ---------------- Phase B: gi = x@Wih^T; GRU combine; la MLPs ----------
    if (bid < 128) {
      const int hc0 = bid * 8;
      Seg sg[1]; sg[0] = { x_ws, (size_t)NH, 0, NH };
      int rows[3] = { hc0 + colsel, NH + hc0 + colsel, 2 * NH + hc0 + colsel };
      tile_gemm<3>(sg, 4, Wih, NH, rows, xbuf, part);
      if (tid < 256) {
        const int b = tid >> 3, hcl = tid & 7, hc = hc0 + hcl;
        float ir = 0.f, iz = 0.f, inn = 0.f;
        #pragma unroll
        for (int w = 0; w < 8; ++w) {
          ir  += part[w * (NB * PSTR) + b * PSTR + hcl];
          iz  += part[w * (NB * PSTR) + b * PSTR + 8 + hcl];
          inn += part[w * (NB * PSTR) + b * PSTR + 16 + hcl];
        }
        ir += bih[hc]; iz += bih[NH + hc]; inn += bih[2 * NH + hc];
        const float hr = gh_ws[b * NH3 + hc];
        const float hz = gh_ws[b * NH3 + NH + hc];
        const float hn = gh_ws[b * NH3 + 2 * NH + hc];
        const float r = sigm(ir + hr);
        const float z = sigm(iz + hz);
        const float n = tanhf(inn + r * hn);
        const float hp = h_ws[b * NH + hc];
        const float hnew = (1.f - z) * n + z * hp;
        h_ws[b * NH + hc] = hnew;
        const size_t o = ((size_t)b * NS + t) * NH + hc;
        out[OH1 + o] = hnew;
        out[OH2 + o] = hnew;
      }
    } else if (bid == 128) {
      for (int i = tid; i < NB * NL * 2; i += 512) {
        const int which = i >> 11;
        const int r2 = i & 2047;
        const int bb = r2 >> 6, l = r2 & 63;
        float a0 = 0.f, a1 = 0.f;
        if (t > 0) {
          a0 = act[((size_t)bb * NS + (t - 1)) * NAA + 0];
          a1 = act[((size_t)bb * NS + (t - 1)) * NAA + 1];
        }
        const float* Wm = which ? qactW : pactW;
        const float* bm = which ? qactb : pactb;
        const float v = lrelu(a0 * Wm[l * NAA + 0] + a1 * Wm[l * NAA + 1] + bm[l]);
        (which ? laq_ws : lap_ws)[bb * NL + l] = v;
      }
    }
    gbar(cntb + (size_t)(t * 4 + 1) * 16, brk);

    // ---------------- Phase C: hmid_q / hmid_p -----------------------------
    if (bid < 132) {
      const int colg = bid * 16;
      Seg sg[3];
      sg[0] = { h_ws, (size_t)NH, 0, NH };
      sg[1] = { emb + (size_t)t * NE, (size_t)NS * NE, NH, NE };
      sg[2] = { laq_ws, (size_t)NL, NH + NE, NL };
      int rows[2] = { colg + colsel, colg + colsel + 8 };
      tile_gemm<2>(sg, 9, W1q, NCQ, rows, xbuf, part);
      const int b = tid >> 4, c = tid & 15;
      hmq_ws[b * NCQ + colg + c] = lrelu(reduce8(part, b, c) + b1q[colg + c]);
    } else if (bid < 200) {
      const int colg = (bid - 132) * 16;
      Seg sg[2];
      sg[0] = { h_ws, (size_t)NH, 0, NH };
      sg[1] = { lap_ws, (size_t)NL, NH, NL };
      int rows[2] = { colg + colsel, colg + colsel + 8 };
      tile_gemm<2>(sg, 5, W1p, NCP, rows, xbuf, part);
      const int b = tid >> 4, c = tid & 15;
      hmp_ws[b * NCP + colg + c] = lrelu(reduce8(part, b, c) + b1p[colg + c]);
    }
    gbar(cntb + (size_t)(t * 4 + 2) * 16, brk);

    // ---------------- Phase D: ml -> mu/sigma/sample -----------------------
    if (bid < 64) {
      const int z0 = bid * 8;
      Seg sg[1]; sg[0] = { hmq_ws, (size_t)NCQ, 0, NCQ };
      int rows[2] = { z0 + colsel, NZ + z0 + colsel };
      tile_gemm<2>(sg, 9, W2q, NCQ, rows, xbuf, part);
      if (tid < 256) {
        const int b = tid >> 3, zl = tid & 7;
        float mu = 0.f, ls = 0.f;
        #pragma unroll
        for (int w = 0; w < 8; ++w) {
          mu += part[w * (NB * PSTR) + b * PSTR + zl];
          ls += part[w * (NB * PSTR) + b * PSTR + 8 + zl];
        }
        mu += b2q[z0 + zl];
        ls += b2q[NZ + z0 + zl];
        const float sgm = 2.f * sigm(0.5f * ls) + 0.1f;
        const size_t o = ((size_t)b * NS + t) * NZ + z0 + zl;
        const float smp = mu + sgm * npo[o];
        out[OSQ + o] = smp;
        out[OMQ + o] = mu;
        out[OGQ + o] = sgm;
        s_ws[b * NZ + z0 + zl] = smp;
      }
    } else if (bid < 128) {
      const int z0 = (bid - 64) * 8;
      Seg sg[1]; sg[0] = { hmp_ws, (size_t)NCP, 0, NCP };
      int rows[2] = { z0 + colsel, NZ + z0 + colsel };
      tile_gemm<2>(sg, 5, W2p, NCP, rows, xbuf, part);
      if (tid < 256) {
        const int b = tid >> 3, zl = tid & 7;
        float mu = 0.f, ls = 0.f;
        #pragma unroll
        for (int w = 0; w < 8; ++w) {
          mu += part[w * (NB * PSTR) + b * PSTR + zl];
          ls += part[w * (NB * PSTR) + b * PSTR + 8 + zl];
        }
        mu += b2p[z0 + zl];
        ls += b2p[NZ + z0 + zl];
        const float sgm = 2.f * sigm(0.5f * ls) + 0.1f;
        const size_t o = ((size_t)b * NS + t) * NZ + z0 + zl;
        const float smp = mu + sgm * npr[o];
        out[OSP + o] = smp;
        out[OMP + o] = mu;
        out[OGP + o] = sgm;
      }
    }
    gbar(cntb + (size_t)(t * 4 + 3) * 16, brk);
  }
}

extern "C" void kernel_launch(void* const* d_in, const int* in_sizes, int n_in,
                              void* d_out, int out_size, void* d_ws, size_t ws_size,
                              hipStream_t stream)
{
  const float* emb   = (const float*)d_in[0];
  const float* act   = (const float*)d_in[1];
  const float* npr   = (const float*)d_in[2];
  const float* npo   = (const float*)d_in[3];
  const float* preW  = (const float*)d_in[4];
  const float* preb  = (const float*)d_in[5];
  const float* Wih   = (const float*)d_in[6];
  const float* Whh   = (const float*)d_in[7];
  const float* bih   = (const float*)d_in[8];
  const float* bhh   = (const float*)d_in[9];
  const float* qactW = (const float*)d_in[10];
  const float* qactb = (const float*)d_in[11];
  const float* pactW = (const float*)d_in[12];
  const float* pactb = (const float*)d_in[13];
  const float* W1q   = (const float*)d_in[14];
  const float* b1q   = (const float*)d_in[15];
  const float* W2q   = (const float*)d_in[16];
  const float* b2q   = (const float*)d_in[17];
  const float* W1p   = (const float*)d_in[18];
  const float* b1p   = (const float*)d_in[19];
  const float* W2p   = (const float*)d_in[20];
  const float* b2p   = (const float*)d_in[21];

  float* out = (float*)d_out;
  float* ws  = (float*)d_ws;
  // ws layout (floats). First 81920 floats are zeroed each call:
  // [s 16384][h 32768][cnt 32768 ints] then scratch.
  float*    s_ws  = ws;
  float*    h_ws  = ws + 16384;
  unsigned* cntb  = (unsigned*)(ws + 49152);        // 2048 barriers * 16-int stride
  unsigned* brk   = cntb + 2048 * 16 - 1;           // last slot of cnt region
  float*    x_ws  = ws + 81920;
  float*    gh_ws = ws + 114688;
  float*    lap_ws = ws + 212992;
  float*    laq_ws = ws + 215040;
  float*    hmq_ws = ws + 217088;
  float*    hmp_ws = ws + 284672;                   // end: 319488 floats (~1.25 MB)

  hipMemsetAsync(ws, 0, (size_t)81920 * sizeof(float), stream);

  rssm_persist<<<256, 512, 0, stream>>>(
      emb, act, npr, npo, preW, preb, Wih, Whh, bih, bhh,
      qactW, qactb, pactW, pactb, W1q, b1q, W2q, b2q, W1p, b1p, W2p, b2p,
      out, s_ws, h_ws, x_ws, gh_ws, lap_ws, laq_ws, hmq_ws, hmp_ws,
      cntb, brk);
}